// Round 7
// baseline (25.015 us; speedup 1.0000x reference)
//
#include <hip/hip_runtime.h>
#include <math.h>

#define BATCH   8
#define NPTS    4096
#define THREADS 512
#define WAVES   8
#define ROWS_PB 128          // rows per block (4 wave row-groups x 32)
#define CHUNK   512          // cols per half per step
#define NSTEP   4            // 2048 cols per half / CHUNK
#define NBLOCKS 512          // (4096/128) * 8 batches * 2 directions

#define NPT_TOT 32768        // B * NPTS per input
#define NBPP    512          // bpp partial blocks
#define LIK_PER_BLK 768      // float4s per bpp block (512*768*4 = 1572864)

typedef __attribute__((ext_vector_type(8)))  __bf16 bf16x8;
typedef __attribute__((ext_vector_type(16))) float  f32x16;

// feature vector [f0..f4] duplicated into both k-halves (lanes l / l+32 hold
// k=0..7 / 8..15 with identical content => MFMA result = 2*d2, halved at end).
__device__ inline bf16x8 packFeat(float f0, float f1, float f2, float f3, float f4) {
    bf16x8 r;
    r[0] = (__bf16)f0; r[1] = (__bf16)f1; r[2] = (__bf16)f2;
    r[3] = (__bf16)f3; r[4] = (__bf16)f4;
    r[5] = (__bf16)0.0f; r[6] = (__bf16)0.0f; r[7] = (__bf16)0.0f;
    return r;
}

// ---------------------------------------------------------------------------
// prep: blocks [0,256) featurize all 65536 point-roles once:
//   feat[input*32768+pt]        = row-feat {x, |x|^2, 1}   (A operand)
//   feat[65536+input*32768+pt]  = col-feat {-2x, 1, |x|^2} (B operand)
// blocks [256,768) compute the 512 bpp partial sums.
// ---------------------------------------------------------------------------
__global__ __launch_bounds__(256) void prep_kernel(
    const float* __restrict__ x_hat, const float* __restrict__ pos,
    const float* __restrict__ lik,
    bf16x8* __restrict__ feat, float* __restrict__ bppPartial)
{
    const int blk = blockIdx.x;
    if (blk < 256) {
        int g = blk * 256 + threadIdx.x;      // 0..65535
        int input = g >> 15, pt = g & (NPT_TOT - 1);
        const float* p = (input ? pos : x_hat) + (size_t)pt * 3;
        float x0 = p[0], x1 = p[1], x2 = p[2];
        float n = fmaf(x0, x0, fmaf(x1, x1, x2 * x2));
        feat[input * NPT_TOT + pt]           = packFeat(x0, x1, x2, n, 1.0f);
        feat[2 * NPT_TOT + input * NPT_TOT + pt] =
            packFeat(-2.f * x0, -2.f * x1, -2.f * x2, 1.0f, n);
    } else {
        int bb = blk - 256;                   // 0..511
        const float4* l4 = (const float4*)lik + (size_t)bb * LIK_PER_BLK;
        float bs = 0.0f;
        for (int i = threadIdx.x; i < LIK_PER_BLK; i += 256) {
            float4 v = l4[i];
            bs -= __log2f(v.x * v.y * v.z * v.w);   // min 1e-24, no underflow
        }
        #pragma unroll
        for (int off = 32; off >= 1; off >>= 1) bs += __shfl_down(bs, off, 64);
        __shared__ float wsum[4];
        int lane = threadIdx.x & 63, w = threadIdx.x >> 6;
        if (lane == 0) wsum[w] = bs;
        __syncthreads();
        if (threadIdx.x == 0)
            bppPartial[bb] = wsum[0] + wsum[1] + wsum[2] + wsum[3];
    }
}

// ---------------------------------------------------------------------------
// fused: chamfer NN-min via MFMA distance tiles, both directions via
// blockIdx.z. 8 waves: wave w owns rows [rowBase + (w>>1)*32, +32), col half
// (w&1). Inner body per B-frag pair: 2 MFMAs -> 16 v_min3 into ONE f32x16.
// Col features are PRECOMPUTED bf16x8 -> staging is 2x(16B load + ds_write).
// ---------------------------------------------------------------------------
__global__ __launch_bounds__(THREADS, 2) void fused_kernel(
    const bf16x8* __restrict__ feat, float* __restrict__ recPartial)
{
    const int z = blockIdx.z;
    const bf16x8* rowF = feat + (z ? NPT_TOT : 0);
    const bf16x8* colF = feat + 2 * NPT_TOT + (z ? 0 : NPT_TOT);

    const int b = blockIdx.y;
    const int rowBase = (int)blockIdx.x * ROWS_PB;
    const int blk = (z * gridDim.y + b) * gridDim.x + blockIdx.x;
    const size_t colBase = (size_t)b * NPTS;

    const int tid  = threadIdx.x;
    const int lane = tid & 63;
    const int w    = tid >> 6;
    const int rg   = w >> 1;     // 0..3 : row group of 32
    const int ph   = w & 1;      // 0/1  : col half
    const int li   = lane & 31;
    const int hi   = lane >> 5;

    __shared__ bf16x8 yfeat[2][2 * CHUNK];  // [buf][flat col] = 32 KB
    __shared__ float  cmb[2][ROWS_PB];
    __shared__ float  wr[WAVES];

    // ---- A fragment: row = rowBase + rg*32 + li ----
    bf16x8 a = rowF[colBase + rowBase + rg * 32 + li];

    f32x16 m, kZero;
    #pragma unroll
    for (int j = 0; j < 16; ++j) { m[j] = 3.0e38f; kZero[j] = 0.0f; }

    {   // prologue: step 0 -> buf 0 (flat col f = tid -> half0, tid+512 -> half1)
        bf16x8 v1 = colF[colBase + tid];
        bf16x8 v2 = colF[colBase + 2048 + tid];
        yfeat[0][tid]       = v1;
        yfeat[0][tid + 512] = v2;
    }
    __syncthreads();

    int buf = 0;
    for (int s = 0; s < NSTEP; ++s) {
        bf16x8 n1, n2;
        if (s + 1 < NSTEP) {   // issue next chunk's loads before compute
            n1 = colF[colBase + (s + 1) * CHUNK + tid];
            n2 = colF[colBase + 2048 + (s + 1) * CHUNK + tid];
        }

        const bf16x8* yb = &yfeat[buf][ph * CHUNK];
        #pragma unroll 2
        for (int f = 0; f < 16; f += 2) {
            bf16x8 bA = yb[f * 32 + li];
            bf16x8 bB = yb[(f + 1) * 32 + li];
            f32x16 d = __builtin_amdgcn_mfma_f32_32x32x16_bf16(a, bA, kZero, 0, 0, 0);
            f32x16 e = __builtin_amdgcn_mfma_f32_32x32x16_bf16(a, bB, kZero, 0, 0, 0);
            #pragma unroll
            for (int j = 0; j < 16; ++j)        // v_min3 fusion
                m[j] = fminf(fminf(d[j], e[j]), m[j]);
        }

        if (s + 1 < NSTEP) {
            yfeat[buf ^ 1][tid]       = n1;
            yfeat[buf ^ 1][tid + 512] = n2;
        }
        __syncthreads();
        buf ^= 1;
    }

    // ---- butterfly min over the 32 col-classes (within each lane-half) ----
    #pragma unroll
    for (int mask = 1; mask <= 16; mask <<= 1)
        #pragma unroll
        for (int j = 0; j < 16; ++j)
            m[j] = fminf(m[j], __shfl_xor(m[j], mask, 64));

    // C/D layout: col=lane&31, row=(reg&3)+8*(reg>>2)+4*(lane>>5)
    if (li == 0) {
        #pragma unroll
        for (int j = 0; j < 16; ++j) {
            int ri = (j & 3) + 8 * (j >> 2) + 4 * hi;
            cmb[ph][rg * 32 + ri] = m[j];
        }
    }
    __syncthreads();

    // ---- block reduce: combine col-halves, halve (k-dup), clamp, sum ----
    float s = 0.0f;
    if (tid < ROWS_PB) {
        float mv = fminf(cmb[0][tid], cmb[1][tid]);
        s = fmaxf(0.5f * mv, 0.0f);
    }
    #pragma unroll
    for (int off = 32; off >= 1; off >>= 1) s += __shfl_down(s, off, 64);
    if (lane == 0) wr[w] = s;
    __syncthreads();
    if (tid == 0) {
        float rs = 0.0f;
        #pragma unroll
        for (int j = 0; j < WAVES; ++j) rs += wr[j];
        recPartial[blk] = rs;
    }
}

// ---------------------------------------------------------------------------
// final: sum the two 512-entry partial arrays; out = {rec+bpp, bpp, rec}
// ---------------------------------------------------------------------------
__global__ __launch_bounds__(256) void final_kernel(const float* __restrict__ recPartial,
                                                    const float* __restrict__ bppPartial,
                                                    float* __restrict__ out) {
    float sr = 0.0f, sb = 0.0f;
    for (int i = threadIdx.x; i < NBLOCKS; i += 256) sr += recPartial[i];
    for (int i = threadIdx.x; i < NBPP;    i += 256) sb += bppPartial[i];
    #pragma unroll
    for (int off = 32; off >= 1; off >>= 1) {
        sr += __shfl_down(sr, off, 64);
        sb += __shfl_down(sb, off, 64);
    }
    __shared__ float wrf[4], wbf[4];
    int lane = threadIdx.x & 63, w = threadIdx.x >> 6;
    if (lane == 0) { wrf[w] = sr; wbf[w] = sb; }
    __syncthreads();
    if (threadIdx.x == 0) {
        float rec = (wrf[0] + wrf[1] + wrf[2] + wrf[3]) * (1.0f / 32768.0f);
        float bpp = (wbf[0] + wbf[1] + wbf[2] + wbf[3]) * (1.0f / 32768.0f);
        out[0] = rec + bpp;
        out[1] = bpp;
        out[2] = rec;
    }
}

extern "C" void kernel_launch(void* const* d_in, const int* in_sizes, int n_in,
                              void* d_out, int out_size, void* d_ws, size_t ws_size,
                              hipStream_t stream) {
    const float* x_hat = (const float*)d_in[0];
    const float* pos   = (const float*)d_in[1];
    const float* lik   = (const float*)d_in[2];
    float* out = (float*)d_out;

    // ws layout: feat bf16x8[4*32768] (2 MB) | recPartial[512] | bppPartial[512]
    bf16x8* feat = (bf16x8*)d_ws;
    float* recPartial = (float*)((char*)d_ws + 4 * (size_t)NPT_TOT * sizeof(bf16x8));
    float* bppPartial = recPartial + NBLOCKS;

    prep_kernel<<<768, 256, 0, stream>>>(x_hat, pos, lik, feat, bppPartial);

    dim3 grid(NPTS / ROWS_PB, BATCH, 2);   // (32, 8, 2) = 512 blocks
    fused_kernel<<<grid, THREADS, 0, stream>>>(feat, recPartial);

    final_kernel<<<1, 256, 0, stream>>>(recPartial, bppPartial, out);
}

// Round 8
// 20.418 us; speedup vs baseline: 1.2252x; 1.2252x over previous
//
#include <hip/hip_runtime.h>
#include <math.h>

#define BATCH   8
#define NPTS    4096
#define THREADS 512
#define WAVES   8
#define ROWS_PB 128          // rows per block (4 wave row-groups x 32)
#define CHUNK   1024         // cols per half per step
#define NSTEP   2            // 2048 cols per half / CHUNK
#define NBLOCKS 512          // (4096/128) * 8 batches * 2 directions
#define NBPP    512

#define LIK_PER_BLK 768      // float4s per block (512*768*4 = 1572864 floats)

typedef __attribute__((ext_vector_type(8)))  __bf16 bf16x8;
typedef __attribute__((ext_vector_type(16))) float  f32x16;

// feature vector [f0..f4] duplicated into both k-halves (lanes l / l+32 hold
// k=0..7 / 8..15 with identical content => MFMA result = 2*d2, halved at end).
__device__ inline bf16x8 packFeat(float f0, float f1, float f2, float f3, float f4) {
    bf16x8 r;
    r[0] = (__bf16)f0; r[1] = (__bf16)f1; r[2] = (__bf16)f2;
    r[3] = (__bf16)f3; r[4] = (__bf16)f4;
    r[5] = (__bf16)0.0f; r[6] = (__bf16)0.0f; r[7] = (__bf16)0.0f;
    return r;
}

__device__ inline bf16x8 colFeat(float y0, float y1, float y2) {
    return packFeat(-2.f * y0, -2.f * y1, -2.f * y2, 1.0f,
                    fmaf(y0, y0, fmaf(y1, y1, y2 * y2)));
}

// ---------------------------------------------------------------------------
// fused: chamfer NN-min via MFMA distance tiles (both directions via
// blockIdx.z) + per-block bpp slice. 8 waves: wave w owns rows
// [rowBase + (w>>1)*32, +32), col half (w&1). Inner body per B-frag pair:
// 2 MFMAs -> 16 v_min3 into ONE f32x16 accumulator. Y features staged in a
// 2x1024-col double buffer: only TWO barriers in the main loop; the single
// prefetch (s=0) issues its 12 global loads before the MFMA sweep.
// ---------------------------------------------------------------------------
__global__ __launch_bounds__(THREADS, 4) void fused_kernel(
    const float* __restrict__ Xin, const float* __restrict__ Yin,
    const float* __restrict__ lik,
    float* __restrict__ recPartial, float* __restrict__ bppPartial)
{
    const float* X; const float* Y;
    if (blockIdx.z == 0) { X = Xin; Y = Yin; }
    else                 { X = Yin; Y = Xin; }

    const int b = blockIdx.y;
    const int rowBase = (int)blockIdx.x * ROWS_PB;
    const int blk = ((int)blockIdx.z * gridDim.y + blockIdx.y) * gridDim.x + blockIdx.x;

    const int tid  = threadIdx.x;
    const int lane = tid & 63;
    const int w    = tid >> 6;
    const int rg   = w >> 1;     // 0..3 : row group of 32
    const int ph   = w & 1;      // 0/1  : col half
    const int li   = lane & 31;
    const int hi   = lane >> 5;

    __shared__ bf16x8 yfeat[2][2 * CHUNK];  // [buf][flat col] = 64 KB
    __shared__ float  cmb[2][ROWS_PB];
    __shared__ float  wr[WAVES], wb[WAVES];

    // ---- bpp slice ----
    float bs = 0.0f;
    {
        const float4* l4 = (const float4*)lik + (size_t)blk * LIK_PER_BLK;
        for (int i = tid; i < LIK_PER_BLK; i += THREADS) {
            float4 v = l4[i];
            bs -= __log2f(v.x * v.y * v.z * v.w);   // min 1e-24, no underflow
        }
    }

    // ---- A fragment: row = rowBase + rg*32 + li ----
    bf16x8 a;
    {
        const float* p = X + ((size_t)b * NPTS + rowBase + rg * 32 + li) * 3;
        float x0 = p[0], x1 = p[1], x2 = p[2];
        a = packFeat(x0, x1, x2, fmaf(x0, x0, fmaf(x1, x1, x2 * x2)), 1.0f);
    }

    f32x16 m, kZero;
    #pragma unroll
    for (int j = 0; j < 16; ++j) { m[j] = 3.0e38f; kZero[j] = 0.0f; }

    const size_t yb0 = (size_t)b * NPTS;

    {   // prologue: step 0 -> buf 0 (4 cols per thread: 2 per half)
        const float* p0 = Y + (yb0 + tid) * 3;
        const float* p1 = Y + (yb0 + 512 + tid) * 3;
        const float* p2 = Y + (yb0 + 2048 + tid) * 3;
        const float* p3 = Y + (yb0 + 2560 + tid) * 3;
        yfeat[0][tid]               = colFeat(p0[0], p0[1], p0[2]);
        yfeat[0][tid + 512]         = colFeat(p1[0], p1[1], p1[2]);
        yfeat[0][CHUNK + tid]       = colFeat(p2[0], p2[1], p2[2]);
        yfeat[0][CHUNK + 512 + tid] = colFeat(p3[0], p3[1], p3[2]);
    }
    __syncthreads();

    int buf = 0;
    for (int s = 0; s < NSTEP; ++s) {
        float u0,u1,u2, v0,v1,v2, t0,t1,t2, q0,q1,q2;
        if (s + 1 < NSTEP) {   // issue next chunk's loads before compute
            const float* p0 = Y + (yb0 + (s + 1) * CHUNK + tid) * 3;
            const float* p1 = p0 + 512 * 3;
            const float* p2 = Y + (yb0 + 2048 + (s + 1) * CHUNK + tid) * 3;
            const float* p3 = p2 + 512 * 3;
            u0 = p0[0]; u1 = p0[1]; u2 = p0[2];
            v0 = p1[0]; v1 = p1[1]; v2 = p1[2];
            t0 = p2[0]; t1 = p2[1]; t2 = p2[2];
            q0 = p3[0]; q1 = p3[1]; q2 = p3[2];
        }

        const bf16x8* yb = &yfeat[buf][ph * CHUNK];
        #pragma unroll 2
        for (int f = 0; f < 32; f += 2) {
            bf16x8 bA = yb[f * 32 + li];
            bf16x8 bB = yb[(f + 1) * 32 + li];
            f32x16 d = __builtin_amdgcn_mfma_f32_32x32x16_bf16(a, bA, kZero, 0, 0, 0);
            f32x16 e = __builtin_amdgcn_mfma_f32_32x32x16_bf16(a, bB, kZero, 0, 0, 0);
            #pragma unroll
            for (int j = 0; j < 16; ++j)        // v_min3 fusion
                m[j] = fminf(fminf(d[j], e[j]), m[j]);
        }

        if (s + 1 < NSTEP) {
            yfeat[buf ^ 1][tid]               = colFeat(u0, u1, u2);
            yfeat[buf ^ 1][tid + 512]         = colFeat(v0, v1, v2);
            yfeat[buf ^ 1][CHUNK + tid]       = colFeat(t0, t1, t2);
            yfeat[buf ^ 1][CHUNK + 512 + tid] = colFeat(q0, q1, q2);
        }
        __syncthreads();
        buf ^= 1;
    }

    // ---- butterfly min over the 32 col-classes (within each lane-half) ----
    #pragma unroll
    for (int mask = 1; mask <= 16; mask <<= 1)
        #pragma unroll
        for (int j = 0; j < 16; ++j)
            m[j] = fminf(m[j], __shfl_xor(m[j], mask, 64));

    // C/D layout: col=lane&31, row=(reg&3)+8*(reg>>2)+4*(lane>>5)
    if (li == 0) {
        #pragma unroll
        for (int j = 0; j < 16; ++j) {
            int ri = (j & 3) + 8 * (j >> 2) + 4 * hi;
            cmb[ph][rg * 32 + ri] = m[j];
        }
    }

    #pragma unroll
    for (int off = 32; off >= 1; off >>= 1) bs += __shfl_down(bs, off, 64);
    if (lane == 0) wb[w] = bs;
    __syncthreads();

    // ---- block reduce: combine col-halves, halve (k-dup), clamp, sum ----
    float s = 0.0f;
    if (tid < ROWS_PB) {
        float mv = fminf(cmb[0][tid], cmb[1][tid]);
        s = fmaxf(0.5f * mv, 0.0f);
    }
    #pragma unroll
    for (int off = 32; off >= 1; off >>= 1) s += __shfl_down(s, off, 64);
    if (lane == 0) wr[w] = s;
    __syncthreads();
    if (tid == 0) {
        float rs = 0.0f, bbv = 0.0f;
        #pragma unroll
        for (int j = 0; j < WAVES; ++j) { rs += wr[j]; bbv += wb[j]; }
        recPartial[blk] = rs;
        bppPartial[blk] = bbv;
    }
}

// ---------------------------------------------------------------------------
// final: sum the two 512-entry partial arrays; out = {rec+bpp, bpp, rec}
// ---------------------------------------------------------------------------
__global__ __launch_bounds__(256) void final_kernel(const float* __restrict__ recPartial,
                                                    const float* __restrict__ bppPartial,
                                                    float* __restrict__ out) {
    float sr = 0.0f, sb = 0.0f;
    for (int i = threadIdx.x; i < NBLOCKS; i += 256) sr += recPartial[i];
    for (int i = threadIdx.x; i < NBPP;    i += 256) sb += bppPartial[i];
    #pragma unroll
    for (int off = 32; off >= 1; off >>= 1) {
        sr += __shfl_down(sr, off, 64);
        sb += __shfl_down(sb, off, 64);
    }
    __shared__ float wrf[4], wbf[4];
    int lane = threadIdx.x & 63, w = threadIdx.x >> 6;
    if (lane == 0) { wrf[w] = sr; wbf[w] = sb; }
    __syncthreads();
    if (threadIdx.x == 0) {
        float rec = (wrf[0] + wrf[1] + wrf[2] + wrf[3]) * (1.0f / 32768.0f);
        float bpp = (wbf[0] + wbf[1] + wbf[2] + wbf[3]) * (1.0f / 32768.0f);
        out[0] = rec + bpp;
        out[1] = bpp;
        out[2] = rec;
    }
}

extern "C" void kernel_launch(void* const* d_in, const int* in_sizes, int n_in,
                              void* d_out, int out_size, void* d_ws, size_t ws_size,
                              hipStream_t stream) {
    const float* x_hat = (const float*)d_in[0];
    const float* pos   = (const float*)d_in[1];
    const float* lik   = (const float*)d_in[2];
    float* out = (float*)d_out;

    // workspace: [0,512) rec partials | [512,1024) bpp partials (floats)
    float* recPartial = (float*)d_ws;
    float* bppPartial = recPartial + NBLOCKS;

    dim3 grid(NPTS / ROWS_PB, BATCH, 2);   // (32, 8, 2) = 512 blocks
    fused_kernel<<<grid, THREADS, 0, stream>>>(x_hat, pos, lik, recPartial, bppPartial);
    final_kernel<<<1, 256, 0, stream>>>(recPartial, bppPartial, out);
}